// Round 6
// baseline (417.266 us; speedup 1.0000x reference)
//
#include <hip/hip_runtime.h>
#include <stdint.h>

#define N_    64
#define CIN   128
#define CMID  256
#define H_    56
#define W_    56
#define OH    28
#define OW    28
#define NPIX  (OH*OW)          // 784
#define CNT_CH (N_*NPIX)       // 50176
#define PXH   58               // padded conv1 input spatial
#define PYH   30               // padded conv2 input spatial
#define EPS_  1e-5f

// ---- stats float indices ----
// 0 sumAbsW1, 1 sumAbsW2, 2 sumAbsWs
// 16 bn1_sum[256], 272 bn1_sq[256], 528 bn2_sum[256], 784 bn2_sq[256]
// 1040 bn2_scale[256], 1296 bn2_off[256], 1552 bn1_A[256], 1808 bn1_B[256]
#define STATS_BYTES 16384
#define OFF_PXI 16384                         // i8 [64][58][58][128] = 27,551,744
#define OFF_PYI (OFF_PXI + 27551744)          // i8 [64][30][30][256] = 14,745,600
#define OFF_W1F (OFF_PYI + 14745600)          // 36*8*1024 = 294,912
#define OFF_W2F (OFF_W1F + 294912)            // 72*8*1024 = 589,824
#define OFF_WSF (OFF_W2F + 589824)            // 4*8*1024  = 32,768
#define MEMSET_BYTES OFF_W1F                  // stats + padded px + padded py zeroed

typedef int v4i  __attribute__((ext_vector_type(4)));
typedef int v16i __attribute__((ext_vector_type(16)));

#define MFMA_I8 __builtin_amdgcn_mfma_i32_32x32x32_i8

typedef const __attribute__((address_space(1))) void* gas_t;
typedef __attribute__((address_space(3))) void* las_t;

// async global->LDS, 16B per lane; LDS dest = base + lane*16; global src per-lane
__device__ __forceinline__ void gl_lds16(const void* g, void* l) {
  __builtin_amdgcn_global_load_lds((gas_t)g, (las_t)l, 16, 0, 0);
}

// x NCHW f32 -> sign i8 NHWC zero-padded [n][58][58][128]
__global__ __launch_bounds__(256) void pack_x_k(const float* __restrict__ x,
                                                int8_t* __restrict__ px) {
  int idx = blockIdx.x * 256 + threadIdx.x;       // 200704
  int n = idx / (H_ * W_), hw = idx - n * (H_ * W_);
  int ih = hw / W_, iw = hw - ih * W_;
  const float* xp = x + ((size_t)n * CIN) * (H_ * W_) + hw;
  uint32_t wd[32];
#pragma unroll
  for (int c4 = 0; c4 < 32; ++c4) {
    uint32_t wv = 0u;
#pragma unroll
    for (int j = 0; j < 4; ++j) {
      uint32_t b = (xp[(size_t)(c4 * 4 + j) * (H_ * W_)] >= 0.f) ? 0x01u : 0xFFu;
      wv |= b << (j * 8);
    }
    wd[c4] = wv;
  }
  uint4* dst = (uint4*)(px + (((size_t)n * (PXH * PXH) + (ih + 1) * PXH + (iw + 1)) * CIN));
#pragma unroll
  for (int q = 0; q < 8; ++q)
    dst[q] = make_uint4(wd[q * 4], wd[q * 4 + 1], wd[q * 4 + 2], wd[q * 4 + 3]);
}

// weight sign bytes pre-packed in MFMA B-fragment order, fused |w| reduction.
// frag (kc, nb): lane l byte j = sign(W[k = kc*32 + (l>>5)*16 + j][o = nb*32 + (l&31)])
__global__ __launch_bounds__(256) void packw1f_k(const float* __restrict__ w1,
                                                 uint32_t* __restrict__ w1f,
                                                 float* __restrict__ stats) {
  int T = blockIdx.x * 256 + threadIdx.x;         // 18432 = 36*8*64
  int l = T & 63, fb = T >> 6;
  int nb = fb & 7, kc = fb >> 3;
  int o = nb * 32 + (l & 31);
  int kbase = kc * 32 + (l >> 5) * 16;
  uint32_t wd[4] = {0u, 0u, 0u, 0u};
  float s = 0.f;
#pragma unroll
  for (int j = 0; j < 16; ++j) {
    int k = kbase + j, t = k >> 7, c = k & 127;
    float wv = w1[((size_t)o * CIN + c) * 9 + t];
    s += fabsf(wv);
    uint32_t b = (wv >= 0.f) ? 0x01u : 0xFFu;
    wd[j >> 2] |= b << ((j & 3) * 8);
  }
  ((uint4*)w1f)[T] = make_uint4(wd[0], wd[1], wd[2], wd[3]);
  for (int off = 32; off; off >>= 1) s += __shfl_down(s, off);
  if ((threadIdx.x & 63) == 0) atomicAdd(&stats[0], s);
}

__global__ __launch_bounds__(256) void packw2f_k(const float* __restrict__ w2,
                                                 uint32_t* __restrict__ w2f,
                                                 float* __restrict__ stats) {
  int T = blockIdx.x * 256 + threadIdx.x;         // 36864 = 72*8*64
  int l = T & 63, fb = T >> 6;
  int nb = fb & 7, kc = fb >> 3;
  int o = nb * 32 + (l & 31);
  int kbase = kc * 32 + (l >> 5) * 16;
  uint32_t wd[4] = {0u, 0u, 0u, 0u};
  float s = 0.f;
#pragma unroll
  for (int j = 0; j < 16; ++j) {
    int k = kbase + j, t = k >> 8, c = k & 255;
    float wv = w2[((size_t)o * CMID + c) * 9 + t];
    s += fabsf(wv);
    uint32_t b = (wv >= 0.f) ? 0x01u : 0xFFu;
    wd[j >> 2] |= b << ((j & 3) * 8);
  }
  ((uint4*)w2f)[T] = make_uint4(wd[0], wd[1], wd[2], wd[3]);
  for (int off = 32; off; off >>= 1) s += __shfl_down(s, off);
  if ((threadIdx.x & 63) == 0) atomicAdd(&stats[1], s);
}

__global__ __launch_bounds__(256) void packwsf_k(const float* __restrict__ ws,
                                                 uint32_t* __restrict__ wsf,
                                                 float* __restrict__ stats) {
  int T = blockIdx.x * 256 + threadIdx.x;         // 2048 = 4*8*64
  int l = T & 63, fb = T >> 6;
  int nb = fb & 7, kc = fb >> 3;
  int o = nb * 32 + (l & 31);
  int kbase = kc * 32 + (l >> 5) * 16;
  uint32_t wd[4] = {0u, 0u, 0u, 0u};
  float s = 0.f;
#pragma unroll
  for (int j = 0; j < 16; ++j) {
    int c = kbase + j;
    float wv = ws[(size_t)o * CIN + c];
    s += fabsf(wv);
    uint32_t b = (wv >= 0.f) ? 0x01u : 0xFFu;
    wd[j >> 2] |= b << ((j & 3) * 8);
  }
  ((uint4*)wsf)[T] = make_uint4(wd[0], wd[1], wd[2], wd[3]);
  for (int off = 32; off; off >>= 1) s += __shfl_down(s, off);
  if ((threadIdx.x & 63) == 0) atomicAdd(&stats[2], s);
}

// conv1: stride-2 3x3, one block = (image, 4-output-row group). N=256 full.
// Stage 9 input rows x 58 cols ONCE into K-major transposed LDS (parity-split
// slots so stride-2 reads are contiguous), then 9 barrier-free unrolled taps
// with direct-global B. Wave (mh,nh) = M64(2 row-frags) x N64.
__global__ __launch_bounds__(512, 4) void conv1_k(const int8_t* __restrict__ px,
                                                  const uint8_t* __restrict__ w1f,
                                                  short* __restrict__ y16,
                                                  float* __restrict__ stats) {
  __shared__ int8_t lds[73728];                   // 8 planes x 576 slots x 16B
  int blk = blockIdx.x;                           // 448 = 8 xcd * 8 img * 7 rg
  int img = (blk & 7) * 8 + ((blk >> 3) & 7);
  int rg  = blk >> 6;                             // 0..6
  int R0  = rg * 4;                               // output rows R0..R0+3
  int tid = threadIdx.x, wv = tid >> 6, l = tid & 63;
  int l31 = l & 31, lhi = l >> 5;
  int mh = wv & 1, nh = wv >> 1;
  const int8_t* imgX = px + (size_t)img * (PXH * PXH * CIN);

  // stage: slot s -> parity p=(s>=288), u=s-288p, ir=u/29, ic=2*(u%29)+p
  for (int i = 0; i < 9; ++i) {
    int c = wv * 9 + i;                           // 72 chunks of 1KB
    int g = c >> 3, q = c & 7;
    int s = g * 64 + l;
    int p = (s >= 288) ? 1 : 0;
    int u = s - p * 288;
    int ir = (u * 1131) >> 15;
    int ic = 2 * (u - ir * 29) + p;
    gl_lds16(imgX + (size_t)(((2 * R0 + ir) * PXH + ic) * CIN + q * 16),
             lds + q * 9216 + g * 1024);
  }
  __syncthreads();

  int m27 = (l31 < 27) ? l31 : 27;
  const uint8_t* pB = w1f + (size_t)l * 16;
  v16i acc[2][2] = {};
#pragma unroll
  for (int t = 0; t < 9; ++t) {
    int kh = t / 3, kw = t - 3 * kh;
    int scol = m27 + (kw >> 1) + (kw & 1) * 288;  // slot col part
#pragma unroll
    for (int kcl = 0; kcl < 4; ++kcl) {
      int q = kcl * 2 + lhi;
      v4i b0 = *(const v4i*)(pB + ((size_t)((t * 4 + kcl) * 8 + nh * 2 + 0) << 10));
      v4i b1 = *(const v4i*)(pB + ((size_t)((t * 4 + kcl) * 8 + nh * 2 + 1) << 10));
      v4i a0 = *(const v4i*)(lds + q * 9216 + ((2 * (mh * 2 + 0) + kh) * 29 + scol) * 16);
      v4i a1 = *(const v4i*)(lds + q * 9216 + ((2 * (mh * 2 + 1) + kh) * 29 + scol) * 16);
      acc[0][0] = MFMA_I8(a0, b0, acc[0][0], 0, 0, 0);
      acc[0][1] = MFMA_I8(a0, b1, acc[0][1], 0, 0, 0);
      acc[1][0] = MFMA_I8(a1, b0, acc[1][0], 0, 0, 0);
      acc[1][1] = MFMA_I8(a1, b1, acc[1][1], 0, 0, 0);
    }
  }

#pragma unroll
  for (int nf = 0; nf < 2; ++nf) {
    int o = nh * 64 + nf * 32 + l31;
    float ssum = 0.f, ssq = 0.f;
#pragma unroll
    for (int fr = 0; fr < 2; ++fr) {
      int oh = R0 + mh * 2 + fr;
#pragma unroll
      for (int r = 0; r < 16; ++r) {
        int owp = (r & 3) + 8 * (r >> 2) + 4 * lhi;
        int d = acc[fr][nf][r];
        bool valid = owp < 28;
        if (valid) y16[((size_t)img * NPIX + oh * 28 + owp) * CMID + o] = (short)d;
        float fd = valid ? (float)d : 0.f;
        ssum += fd; ssq += fd * fd;
      }
    }
    ssum += __shfl_down(ssum, 32);
    ssq  += __shfl_down(ssq, 32);
    if (l < 32) { atomicAdd(&stats[16 + o], ssum); atomicAdd(&stats[272 + o], ssq); }
  }
}

__global__ void bn1_prep_k(float* __restrict__ stats,
                           const float* __restrict__ g1,
                           const float* __restrict__ b1) {
  int c = threadIdx.x;                            // 1 x 256
  float alpha1 = stats[0] * (1.f / (CMID * CIN * 9));
  float S = stats[16 + c], S2 = stats[272 + c];
  float mu = alpha1 * (S * (1.f / CNT_CH));
  float ey2 = alpha1 * alpha1 * (S2 * (1.f / CNT_CH));
  float var = fmaxf(ey2 - mu * mu, 0.f);
  float rs = rsqrtf(var + EPS_);
  float g = g1[c];
  stats[1552 + c] = g * rs * alpha1;
  stats[1808 + c] = b1[c] - g * rs * mu;
}

// BN1 + sign -> py i8 NHWC padded [n][30][30][256]
__global__ __launch_bounds__(256) void pack_y_k(const short* __restrict__ y16,
                                                const float* __restrict__ stats,
                                                int8_t* __restrict__ py) {
  int gid = blockIdx.x * 256 + threadIdx.x;       // 1,605,632 = 6272*256
  int cg = gid & 31, pix = gid >> 5;
  int n = pix / NPIX, hw = pix - n * NPIX;
  int oh = hw / OW, ow = hw - oh * OW;
  uint4 raw = *(const uint4*)(y16 + (size_t)pix * CMID + cg * 8);
  const float* A = stats + 1552 + cg * 8;
  const float* B = stats + 1808 + cg * 8;
  float4 A0 = *(const float4*)A, A1 = *(const float4*)(A + 4);
  float4 B0 = *(const float4*)B, B1 = *(const float4*)(B + 4);
  int s[8];
  s[0] = (int)(short)(raw.x & 0xFFFF); s[1] = ((int)raw.x) >> 16;
  s[2] = (int)(short)(raw.y & 0xFFFF); s[3] = ((int)raw.y) >> 16;
  s[4] = (int)(short)(raw.z & 0xFFFF); s[5] = ((int)raw.z) >> 16;
  s[6] = (int)(short)(raw.w & 0xFFFF); s[7] = ((int)raw.w) >> 16;
  float a[8] = {A0.x, A0.y, A0.z, A0.w, A1.x, A1.y, A1.z, A1.w};
  float b[8] = {B0.x, B0.y, B0.z, B0.w, B1.x, B1.y, B1.z, B1.w};
  uint32_t w0 = 0u, w1 = 0u;
#pragma unroll
  for (int j = 0; j < 4; ++j) {
    w0 |= ((fmaf(a[j], (float)s[j], b[j]) >= 0.f) ? 0x01u : 0xFFu) << (j * 8);
    w1 |= ((fmaf(a[4 + j], (float)s[4 + j], b[4 + j]) >= 0.f) ? 0x01u : 0xFFu) << (j * 8);
  }
  size_t off = ((size_t)n * (PYH * PYH) + (oh + 1) * PYH + (ow + 1)) * CMID + cg * 8;
  *(uint2*)(py + off) = make_uint2(w0, w1);
}

// conv2 + fused 1x1 shortcut. One block = (image, 8-output-row group), N=256.
// Phase 1: stage shortcut px span (32KB), compute as into acc, acc <<= 13.
// Phase 2: stage 10 input rows x 30 cols of py ONCE (80KB K-major transposed),
// then 18 barrier-free unrolled half-taps accumulate am on top.
// Epilogue splits acc = 8192*as + am exactly (|as|<=128, |am|<=2304<4096).
__global__ __launch_bounds__(512, 2) void conv2_k(const int8_t* __restrict__ py,
                                                  const int8_t* __restrict__ px,
                                                  const uint8_t* __restrict__ w2f,
                                                  const uint8_t* __restrict__ wsf,
                                                  const float* __restrict__ stats,
                                                  float* __restrict__ out,
                                                  float* __restrict__ statw) {
  __shared__ int8_t lds[81920];                   // 16 planes x 320 slots x 16B
  int blk = blockIdx.x;                           // 256 = 8 xcd * 8 img * 4 rg
  int img = (blk & 7) * 8 + ((blk >> 3) & 7);
  int rg = blk >> 6;                              // 0..3
  int R0 = rg * 8;                                // output rows R0..R0+7 (>=28 masked)
  int tid = threadIdx.x, wv = tid >> 6, l = tid & 63;
  int l31 = l & 31, lhi = l >> 5;
  int mh = wv & 1, nh = wv >> 1;                  // wave: M128 (4 row-frags) x N64

  // ---- phase 1: shortcut (K=128 from px center taps) ----
  const int8_t* imgX = px + (size_t)img * (PXH * PXH * CIN);
  for (int i = 0; i < 4; ++i) {
    int c = wv * 4 + i;                           // 32 chunks
    int g = c >> 3, q = c & 7;
    int s = g * 64 + l;                           // slot = r*32 + owp
    int r = s >> 5, owp = s & 31;
    int rr = R0 + r; if (rr > 27) rr = 27;
    int cc = (owp < 27) ? owp : 27;
    gl_lds16(imgX + (size_t)(((2 * rr + 1) * PXH + 2 * cc + 1) * CIN + q * 16),
             lds + q * 4096 + g * 1024);
  }
  __syncthreads();

  v16i acc[4][2] = {};
  {
    const uint8_t* sB = wsf + (size_t)l * 16;
#pragma unroll
    for (int kcl = 0; kcl < 4; ++kcl) {
      int q = kcl * 2 + lhi;
      v4i b0 = *(const v4i*)(sB + ((size_t)(kcl * 8 + nh * 2 + 0) << 10));
      v4i b1 = *(const v4i*)(sB + ((size_t)(kcl * 8 + nh * 2 + 1) << 10));
#pragma unroll
      for (int fr = 0; fr < 4; ++fr) {
        int s = (mh * 4 + fr) * 32 + l31;
        v4i a = *(const v4i*)(lds + q * 4096 + s * 16);
        acc[fr][0] = MFMA_I8(a, b0, acc[fr][0], 0, 0, 0);
        acc[fr][1] = MFMA_I8(a, b1, acc[fr][1], 0, 0, 0);
      }
    }
  }
#pragma unroll
  for (int fr = 0; fr < 4; ++fr)
#pragma unroll
    for (int nf = 0; nf < 2; ++nf)
#pragma unroll
      for (int r = 0; r < 16; ++r)
        acc[fr][nf][r] <<= 13;                    // acc = 8192 * as
  __syncthreads();                                // all done reading sc region

  // ---- phase 2: main conv (K=2304) ----
  const int8_t* imgY = py + (size_t)img * (PYH * PYH * CMID);
  for (int i = 0; i < 10; ++i) {
    int c = wv * 10 + i;                          // 80 chunks
    int g = c >> 4, q = c & 15;
    int s = g * 64 + l;                           // slot = ir*30 + ic, 0..319
    int ir = (s * 1093) >> 15;
    int ic = s - ir * 30;
    int row = R0 + ir; if (row > 29) row = 29;    // clamp (masked rows only)
    gl_lds16(imgY + (size_t)((row * PYH + ic) * CMID + q * 16),
             lds + q * 5120 + g * 1024);
  }
  __syncthreads();

  int m27 = (l31 < 27) ? l31 : 27;
  const uint8_t* pB = w2f + (size_t)l * 16;
#pragma unroll
  for (int j = 0; j < 18; ++j) {                  // half-taps, K=128 each
    int t = j >> 1, h = j & 1;
    int kh = t / 3, kw = t - 3 * kh;
#pragma unroll
    for (int kcl = 0; kcl < 4; ++kcl) {
      int q = (h * 4 + kcl) * 2 + lhi;            // 0..15
      v4i b0 = *(const v4i*)(pB + ((size_t)((j * 4 + kcl) * 8 + nh * 2 + 0) << 10));
      v4i b1 = *(const v4i*)(pB + ((size_t)((j * 4 + kcl) * 8 + nh * 2 + 1) << 10));
#pragma unroll
      for (int fr = 0; fr < 4; ++fr) {
        int slot = (mh * 4 + fr + kh) * 30 + m27 + kw;
        v4i a = *(const v4i*)(lds + q * 5120 + slot * 16);
        acc[fr][0] = MFMA_I8(a, b0, acc[fr][0], 0, 0, 0);
        acc[fr][1] = MFMA_I8(a, b1, acc[fr][1], 0, 0, 0);
      }
    }
  }

  float a2  = stats[1] * (1.f / (CMID * CMID * 9));
  float asx = stats[2] * (1.f / (CMID * CIN));
#pragma unroll
  for (int nf = 0; nf < 2; ++nf) {
    int o = nh * 64 + nf * 32 + l31;
    float ssum = 0.f, ssq = 0.f;
#pragma unroll
    for (int fr = 0; fr < 4; ++fr) {
      int oh = R0 + mh * 4 + fr;
#pragma unroll
      for (int r = 0; r < 16; ++r) {
        int owp = (r & 3) + 8 * (r >> 2) + 4 * lhi;
        int t32 = acc[fr][nf][r];
        int as_ = (t32 + 4096) >> 13;             // exact: |am|<4096
        int am_ = t32 - (as_ << 13);
        float v = a2 * (float)am_ + asx * (float)as_;
        bool valid = (owp < 28) && (oh < 28);
        if (valid) out[((size_t)img * CMID + o) * NPIX + oh * 28 + owp] = v;
        float vm = valid ? v : 0.f;
        ssum += vm; ssq += vm * vm;
      }
    }
    ssum += __shfl_down(ssum, 32);
    ssq  += __shfl_down(ssq, 32);
    if (l < 32) { atomicAdd(&statw[528 + o], ssum); atomicAdd(&statw[784 + o], ssq); }
  }
}

__global__ void bn2_prep_k(float* __restrict__ stats,
                           const float* __restrict__ g2,
                           const float* __restrict__ b2) {
  int c = threadIdx.x;                            // 1 x 256
  float S = stats[528 + c], S2 = stats[784 + c];
  float mu = S * (1.f / CNT_CH);
  float var = fmaxf(S2 * (1.f / CNT_CH) - mu * mu, 0.f);
  float rs = rsqrtf(var + EPS_);
  float g = g2[c];
  stats[1040 + c] = g * rs;
  stats[1296 + c] = b2[c] - g * rs * mu;
}

__global__ __launch_bounds__(256) void bn2_apply_k(float4* __restrict__ out,
                                                   const float* __restrict__ stats) {
  int idx = blockIdx.x * 256 + threadIdx.x;       // 3,211,264 float4s = 12544 blocks
  int c = (idx / (NPIX / 4)) & (CMID - 1);
  float sc = stats[1040 + c], of = stats[1296 + c];
  float4 v = out[idx];
  v.x = v.x * sc + of; v.y = v.y * sc + of; v.z = v.z * sc + of; v.w = v.w * sc + of;
  out[idx] = v;
}

extern "C" void kernel_launch(void* const* d_in, const int* in_sizes, int n_in,
                              void* d_out, int out_size, void* d_ws, size_t ws_size,
                              hipStream_t stream) {
  const float* x   = (const float*)d_in[0];
  const float* w1  = (const float*)d_in[1];
  const float* g1  = (const float*)d_in[2];
  const float* b1  = (const float*)d_in[3];
  const float* w2  = (const float*)d_in[4];
  const float* g2  = (const float*)d_in[5];
  const float* b2  = (const float*)d_in[6];
  const float* wsc = (const float*)d_in[7];
  float* out = (float*)d_out;

  char* ws = (char*)d_ws;
  float*    stats = (float*)ws;
  int8_t*   pxi = (int8_t*)(ws + OFF_PXI);
  int8_t*   pyi = (int8_t*)(ws + OFF_PYI);
  uint32_t* w1f = (uint32_t*)(ws + OFF_W1F);
  uint32_t* w2f = (uint32_t*)(ws + OFF_W2F);
  uint32_t* wsf = (uint32_t*)(ws + OFF_WSF);
  short*    y16 = (short*)d_out;                  // conv1 raw dots, dead after pack_y

  hipMemsetAsync(ws, 0, MEMSET_BYTES, stream);    // stats + padded px + padded py

  pack_x_k<<<784, 256, 0, stream>>>(x, pxi);
  packw1f_k<<<72, 256, 0, stream>>>(w1, w1f, stats);
  packw2f_k<<<144, 256, 0, stream>>>(w2, w2f, stats);
  packwsf_k<<<8, 256, 0, stream>>>(wsc, wsf, stats);

  conv1_k<<<448, 512, 0, stream>>>(pxi, (const uint8_t*)w1f, y16, stats);
  bn1_prep_k<<<1, 256, 0, stream>>>(stats, g1, b1);
  pack_y_k<<<6272, 256, 0, stream>>>(y16, stats, pyi);
  conv2_k<<<256, 512, 0, stream>>>(pyi, pxi, (const uint8_t*)w2f, (const uint8_t*)wsf,
                                   stats, out, stats);
  bn2_prep_k<<<1, 256, 0, stream>>>(stats, g2, b2);
  bn2_apply_k<<<12544, 256, 0, stream>>>((float4*)out, stats);
}

// Round 7
// 340.240 us; speedup vs baseline: 1.2264x; 1.2264x over previous
//
#include <hip/hip_runtime.h>
#include <stdint.h>

#define N_    64
#define CIN   128
#define CMID  256
#define H_    56
#define W_    56
#define OH    28
#define OW    28
#define NPIX  (OH*OW)          // 784
#define MPAD  800              // per-image M padded to 25*32
#define MTOT  (N_*MPAD)        // 51200
#define CNT_CH (N_*NPIX)       // 50176
#define PXH   58               // padded conv1 input spatial
#define PYH   30               // padded conv2 input spatial
#define EPS_  1e-5f

// ---- stats float indices ----
// 0 sumAbsW1, 1 sumAbsW2, 2 sumAbsWs
// 16 bn1_sum[256], 272 bn1_sq[256], 528 bn2_sum[256], 784 bn2_sq[256]
#define STATS_BYTES 16384
#define OFF_PXI 16384                         // i8 [64][58][58][128] = 27,551,744
#define OFF_PYI (OFF_PXI + 27551744)          // i8 [64][30][30][256] = 14,745,600
#define OFF_W1F (OFF_PYI + 14745600)          // 36*8*1024 = 294,912
#define OFF_W2F (OFF_W1F + 294912)            // 72*8*1024 = 589,824
#define OFF_WSF (OFF_W2F + 589824)            // 4*8*1024  = 32,768

typedef int v4i  __attribute__((ext_vector_type(4)));
typedef int v16i __attribute__((ext_vector_type(16)));

#define MFMA_I8 __builtin_amdgcn_mfma_i32_32x32x32_i8

typedef const __attribute__((address_space(1))) void* gas_t;
typedef __attribute__((address_space(3))) void* las_t;

// async global->LDS, 16B per lane; LDS dest = base + lane*16 (wave-uniform base)
__device__ __forceinline__ void gl_lds16(const void* g, void* l) {
  __builtin_amdgcn_global_load_lds((gas_t)g, (las_t)l, 16, 0, 0);
}

// x NCHW f32 -> sign i8 NHWC zero-padded [n][58][58][128]; pad branch zeroes ring
__global__ __launch_bounds__(256) void pack_x_k(const float* __restrict__ x,
                                                int8_t* __restrict__ px) {
  if (blockIdx.x >= 784) {                        // pad-zero branch: 456 blocks
    int t = (blockIdx.x - 784) * 256 + threadIdx.x;   // 116736 = 64*228*8
    int q = t & 7, pp = t >> 3;
    int n = pp / 228, p = pp - n * 228;
    int ih, iw;
    if (p < 58)        { ih = 0;  iw = p; }
    else if (p < 116)  { ih = 57; iw = p - 58; }
    else { int qq = p - 116; ih = 1 + (qq >> 1); iw = (qq & 1) * 57; }
    uint4* dst = (uint4*)(px + ((size_t)n * (PXH * PXH) + ih * PXH + iw) * CIN);
    dst[q] = make_uint4(0u, 0u, 0u, 0u);
    return;
  }
  int idx = blockIdx.x * 256 + threadIdx.x;       // 200704
  int n = idx / (H_ * W_), hw = idx - n * (H_ * W_);
  int ih = hw / W_, iw = hw - ih * W_;
  const float* xp = x + ((size_t)n * CIN) * (H_ * W_) + hw;
  uint32_t wd[32];
#pragma unroll
  for (int c4 = 0; c4 < 32; ++c4) {
    uint32_t wv = 0u;
#pragma unroll
    for (int j = 0; j < 4; ++j) {
      uint32_t b = (xp[(size_t)(c4 * 4 + j) * (H_ * W_)] >= 0.f) ? 0x01u : 0xFFu;
      wv |= b << (j * 8);
    }
    wd[c4] = wv;
  }
  uint4* dst = (uint4*)(px + (((size_t)n * (PXH * PXH) + (ih + 1) * PXH + (iw + 1)) * CIN));
#pragma unroll
  for (int q = 0; q < 8; ++q)
    dst[q] = make_uint4(wd[q * 4], wd[q * 4 + 1], wd[q * 4 + 2], wd[q * 4 + 3]);
}

// fused weight pack (all 3 weights) + |w| reductions.
// frag (kc, nb): lane l byte j = sign(W[k = kc*32 + (l>>5)*16 + j][o = nb*32 + (l&31)])
__global__ __launch_bounds__(256) void packw_all_k(const float* __restrict__ w1,
                                                   const float* __restrict__ w2,
                                                   const float* __restrict__ ws,
                                                   uint32_t* __restrict__ w1f,
                                                   uint32_t* __restrict__ w2f,
                                                   uint32_t* __restrict__ wsf,
                                                   float* __restrict__ stats) {
  int bx = blockIdx.x;
  float s = 0.f;
  if (bx < 72) {                                  // w1: 18432 frag-lanes
    int T = bx * 256 + threadIdx.x;
    int l = T & 63, fb = T >> 6;
    int nb = fb & 7, kc = fb >> 3;
    int o = nb * 32 + (l & 31);
    int kbase = kc * 32 + (l >> 5) * 16;
    uint32_t wd[4] = {0u, 0u, 0u, 0u};
#pragma unroll
    for (int j = 0; j < 16; ++j) {
      int k = kbase + j, t = k >> 7, c = k & 127;
      float wv = w1[((size_t)o * CIN + c) * 9 + t];
      s += fabsf(wv);
      wd[j >> 2] |= ((wv >= 0.f) ? 0x01u : 0xFFu) << ((j & 3) * 8);
    }
    ((uint4*)w1f)[T] = make_uint4(wd[0], wd[1], wd[2], wd[3]);
    for (int off = 32; off; off >>= 1) s += __shfl_down(s, off);
    if ((threadIdx.x & 63) == 0) atomicAdd(&stats[0], s);
  } else if (bx < 216) {                          // w2: 36864 frag-lanes
    int T = (bx - 72) * 256 + threadIdx.x;
    int l = T & 63, fb = T >> 6;
    int nb = fb & 7, kc = fb >> 3;
    int o = nb * 32 + (l & 31);
    int kbase = kc * 32 + (l >> 5) * 16;
    uint32_t wd[4] = {0u, 0u, 0u, 0u};
#pragma unroll
    for (int j = 0; j < 16; ++j) {
      int k = kbase + j, t = k >> 8, c = k & 255;
      float wv = w2[((size_t)o * CMID + c) * 9 + t];
      s += fabsf(wv);
      wd[j >> 2] |= ((wv >= 0.f) ? 0x01u : 0xFFu) << ((j & 3) * 8);
    }
    ((uint4*)w2f)[T] = make_uint4(wd[0], wd[1], wd[2], wd[3]);
    for (int off = 32; off; off >>= 1) s += __shfl_down(s, off);
    if ((threadIdx.x & 63) == 0) atomicAdd(&stats[1], s);
  } else {                                        // ws: 2048 frag-lanes
    int T = (bx - 216) * 256 + threadIdx.x;
    int l = T & 63, fb = T >> 6;
    int nb = fb & 7, kc = fb >> 3;
    int o = nb * 32 + (l & 31);
    int kbase = kc * 32 + (l >> 5) * 16;
    uint32_t wd[4] = {0u, 0u, 0u, 0u};
#pragma unroll
    for (int j = 0; j < 16; ++j) {
      int c = kbase + j;
      float wv = ws[(size_t)o * CIN + c];
      s += fabsf(wv);
      wd[j >> 2] |= ((wv >= 0.f) ? 0x01u : 0xFFu) << ((j & 3) * 8);
    }
    ((uint4*)wsf)[T] = make_uint4(wd[0], wd[1], wd[2], wd[3]);
    for (int off = 32; off; off >>= 1) s += __shfl_down(s, off);
    if ((threadIdx.x & 63) == 0) atomicAdd(&stats[2], s);
  }
}

// conv1: implicit GEMM, M=51200 (padded pixels), N=256, K=9*128.
// LDS-staged double-buffered pipeline + XCD-bijective block swizzle (r5/best).
__global__ __launch_bounds__(256, 2) void conv1_k(const int8_t* __restrict__ px,
                                                  const uint8_t* __restrict__ w1f,
                                                  short* __restrict__ y16,
                                                  float* __restrict__ stats) {
  __shared__ int8_t lds[2][32768];                // per buf: A 16KB @0, B 16KB @16384
  int bid = (blockIdx.x & 7) * 100 + (blockIdx.x >> 3);  // bijective, 800%8==0
  int bnh = bid & 1, bm = bid >> 1;               // 400 M x 2 N
  int tid = threadIdx.x, w = tid >> 6, l = tid & 63;
  int l31 = l & 31, lhi = l >> 5;
  int blockM = bm * 128;
  int waveM = blockM + (w & 1) * 64;
  int waveN = bnh * 128 + (w >> 1) * 64;
  int nbgl2 = (w >> 1) * 2;

  int srcsw = (((l & 7) ^ (l >> 3)) << 4);
  uint32_t rowoff[4];
#pragma unroll
  for (int i = 0; i < 4; ++i) {
    int p = blockM + (w * 4 + i) * 8 + (l >> 3);
    int n = p / MPAD, hw = p - n * MPAD;
    if (hw >= NPIX) hw = 0;                       // pad rows: safe in-image source
    int oh = hw / OW, ow = hw - oh * OW;
    rowoff[i] = (uint32_t)((n * (PXH * PXH) + (2 * oh) * PXH + 2 * ow) * CIN);
  }
  int sw = (l31 & 7) << 4;
  uint32_t aoff[2][4];
#pragma unroll
  for (int m = 0; m < 2; ++m) {
    int pxl = (w & 1) * 64 + m * 32 + l31;
#pragma unroll
    for (int kcl = 0; kcl < 4; ++kcl)
      aoff[m][kcl] = (uint32_t)(pxl * 128 + ((kcl * 32 + lhi * 16) ^ sw));
  }

  v16i acc[2][2] = {};

  auto stage = [&](int t, int8_t* buf) {
    int kh = t / 3, kw = t - 3 * kh;
    uint32_t tapoff = (uint32_t)((kh * PXH + kw) * CIN);
#pragma unroll
    for (int i = 0; i < 4; ++i) {
      int ch = w * 4 + i;
      gl_lds16(px + (size_t)(rowoff[i] + tapoff) + srcsw, buf + ch * 1024);
      gl_lds16(w1f + ((size_t)(((t * 4 + w) * 8) + bnh * 4 + i) << 10) + l * 16,
               buf + 16384 + ch * 1024);
    }
  };

  stage(0, lds[0]);
  __syncthreads();
  for (int it = 0; it < 9; ++it) {
    if (it < 8) stage(it + 1, lds[(it + 1) & 1]);
    const int8_t* cbuf = lds[it & 1];
    v4i a[2][4], b[2][4];
#pragma unroll
    for (int m = 0; m < 2; ++m)
#pragma unroll
      for (int kcl = 0; kcl < 4; ++kcl)
        a[m][kcl] = *(const v4i*)(cbuf + aoff[m][kcl]);
#pragma unroll
    for (int n2 = 0; n2 < 2; ++n2)
#pragma unroll
      for (int kcl = 0; kcl < 4; ++kcl)
        b[n2][kcl] = *(const v4i*)(cbuf + 16384 + (kcl * 4 + nbgl2 + n2) * 1024 + l * 16);
#pragma unroll
    for (int kcl = 0; kcl < 4; ++kcl) {
      acc[0][0] = MFMA_I8(a[0][kcl], b[0][kcl], acc[0][0], 0, 0, 0);
      acc[0][1] = MFMA_I8(a[0][kcl], b[1][kcl], acc[0][1], 0, 0, 0);
      acc[1][0] = MFMA_I8(a[1][kcl], b[0][kcl], acc[1][0], 0, 0, 0);
      acc[1][1] = MFMA_I8(a[1][kcl], b[1][kcl], acc[1][1], 0, 0, 0);
    }
    __syncthreads();
  }

#pragma unroll
  for (int n2 = 0; n2 < 2; ++n2) {
    int o = waveN + n2 * 32 + l31;
    float ssum = 0.f, ssq = 0.f;
#pragma unroll
    for (int m = 0; m < 2; ++m) {
      int tbase = waveM + m * 32;
      int nb0 = tbase / MPAD, r0 = tbase - nb0 * MPAD;   // 32-aligned: never crosses image
#pragma unroll
      for (int r = 0; r < 16; ++r) {
        int row = (r & 3) + 8 * (r >> 2) + 4 * lhi;
        int hwr = r0 + row;
        int d = acc[m][n2][r];
        bool valid = hwr < NPIX;
        if (valid) y16[((size_t)nb0 * NPIX + hwr) * CMID + o] = (short)d;
        float fd = valid ? (float)d : 0.f;
        ssum += fd; ssq += fd * fd;
      }
    }
    ssum += __shfl_down(ssum, 32);
    ssq  += __shfl_down(ssq, 32);
    if (l < 32) { atomicAdd(&stats[16 + o], ssum); atomicAdd(&stats[272 + o], ssq); }
  }
}

// BN1 (recomputed inline from raw sums) + sign -> py i8 NHWC padded [n][30][30][256]
// pad branch zeroes the ring.
__global__ __launch_bounds__(256) void pack_y_k(const short* __restrict__ y16,
                                                const float* __restrict__ stats,
                                                const float* __restrict__ g1,
                                                const float* __restrict__ b1,
                                                int8_t* __restrict__ py) {
  if (blockIdx.x >= 6272) {                       // pad-zero branch: 464 blocks
    int t = (blockIdx.x - 6272) * 256 + threadIdx.x;  // 118784 = 64*116*16
    int q = t & 15, pp = t >> 4;
    int n = pp / 116, p = pp - n * 116;
    int ih, iw;
    if (p < 30)       { ih = 0;  iw = p; }
    else if (p < 60)  { ih = 29; iw = p - 30; }
    else { int qq = p - 60; ih = 1 + (qq >> 1); iw = (qq & 1) * 29; }
    uint4* dst = (uint4*)(py + ((size_t)n * (PYH * PYH) + ih * PYH + iw) * CMID);
    dst[q] = make_uint4(0u, 0u, 0u, 0u);
    return;
  }
  int gid = blockIdx.x * 256 + threadIdx.x;       // 1,605,632 = 6272*256
  int cg = gid & 31, pix = gid >> 5;
  int n = pix / NPIX, hw = pix - n * NPIX;
  int oh = hw / OW, ow = hw - oh * OW;
  uint4 raw = *(const uint4*)(y16 + (size_t)pix * CMID + cg * 8);
  float alpha1 = stats[0] * (1.f / (CMID * CIN * 9));
  float a[8], b[8];
#pragma unroll
  for (int j = 0; j < 8; ++j) {
    int c = cg * 8 + j;
    float S = stats[16 + c], S2 = stats[272 + c];
    float mu = alpha1 * (S * (1.f / CNT_CH));
    float ey2 = alpha1 * alpha1 * (S2 * (1.f / CNT_CH));
    float var = fmaxf(ey2 - mu * mu, 0.f);
    float rs = rsqrtf(var + EPS_);
    float g = g1[c];
    a[j] = g * rs * alpha1;
    b[j] = b1[c] - g * rs * mu;
  }
  int s[8];
  s[0] = (int)(short)(raw.x & 0xFFFF); s[1] = ((int)raw.x) >> 16;
  s[2] = (int)(short)(raw.y & 0xFFFF); s[3] = ((int)raw.y) >> 16;
  s[4] = (int)(short)(raw.z & 0xFFFF); s[5] = ((int)raw.z) >> 16;
  s[6] = (int)(short)(raw.w & 0xFFFF); s[7] = ((int)raw.w) >> 16;
  uint32_t w0 = 0u, w1 = 0u;
#pragma unroll
  for (int j = 0; j < 4; ++j) {
    w0 |= ((fmaf(a[j], (float)s[j], b[j]) >= 0.f) ? 0x01u : 0xFFu) << (j * 8);
    w1 |= ((fmaf(a[4 + j], (float)s[4 + j], b[4 + j]) >= 0.f) ? 0x01u : 0xFFu) << (j * 8);
  }
  size_t off = ((size_t)n * (PYH * PYH) + (oh + 1) * PYH + (ow + 1)) * CMID + cg * 8;
  *(uint2*)(py + off) = make_uint2(w0, w1);
}

// conv2 + fused 1x1 shortcut: M=51200, N=256, K=9*256 (+128 shortcut). r5/best.
__global__ __launch_bounds__(256, 2) void conv2_k(const int8_t* __restrict__ py,
                                                  const int8_t* __restrict__ px,
                                                  const uint8_t* __restrict__ w2f,
                                                  const uint8_t* __restrict__ wsf,
                                                  const float* __restrict__ stats,
                                                  float* __restrict__ out,
                                                  float* __restrict__ statw) {
  __shared__ int8_t lds[2][32768];                // per buf: A 16KB @0, B 16KB @16384
  int bid = (blockIdx.x & 7) * 100 + (blockIdx.x >> 3);  // bijective, 800%8==0
  int bnh = bid & 1, bm = bid >> 1;
  int tid = threadIdx.x, w = tid >> 6, l = tid & 63;
  int l31 = l & 31, lhi = l >> 5;
  int blockM = bm * 128;
  int waveM = blockM + (w & 1) * 64;
  int waveN = bnh * 128 + (w >> 1) * 64;
  int nbgl2 = (w >> 1) * 2;

  int srcsw = (((l & 7) ^ (l >> 3)) << 4);
  uint32_t rowoff[4], sxoff[4];
#pragma unroll
  for (int i = 0; i < 4; ++i) {
    int p = blockM + (w * 4 + i) * 8 + (l >> 3);
    int n = p / MPAD, hw = p - n * MPAD;
    if (hw >= NPIX) hw = 0;                       // pad rows: safe in-image source
    int oh = hw / OW, ow = hw - oh * OW;
    rowoff[i] = (uint32_t)((n * (PYH * PYH) + oh * PYH + ow) * CMID);
    sxoff[i]  = (uint32_t)((n * (PXH * PXH) + (2 * oh + 1) * PXH + (2 * ow + 1)) * CIN);
  }
  int sw = (l31 & 7) << 4;
  uint32_t aoff[2][4];
#pragma unroll
  for (int m = 0; m < 2; ++m) {
    int pxl = (w & 1) * 64 + m * 32 + l31;
#pragma unroll
    for (int kcl = 0; kcl < 4; ++kcl)
      aoff[m][kcl] = (uint32_t)(pxl * 128 + ((kcl * 32 + lhi * 16) ^ sw));
  }

  v16i am[2][2] = {};

  auto stageM = [&](int j, int8_t* buf) {        // j in [0,18): half-tap
    int t = j >> 1, h = j & 1;
    int kh = t / 3, kw = t - 3 * kh;
    uint32_t tapoff = (uint32_t)((kh * PYH + kw) * CMID + h * 128);
    int kc = t * 8 + h * 4 + w;                  // B: kcl = w
#pragma unroll
    for (int i = 0; i < 4; ++i) {
      int ch = w * 4 + i;
      gl_lds16(py + (size_t)(rowoff[i] + tapoff) + srcsw, buf + ch * 1024);
      gl_lds16(w2f + ((size_t)(kc * 8 + bnh * 4 + i) << 10) + l * 16,
               buf + 16384 + ch * 1024);
    }
  };
  auto computeM = [&](const int8_t* cbuf, v16i (&ac)[2][2]) {
    v4i a[2][4], b[2][4];
#pragma unroll
    for (int m = 0; m < 2; ++m)
#pragma unroll
      for (int kcl = 0; kcl < 4; ++kcl)
        a[m][kcl] = *(const v4i*)(cbuf + aoff[m][kcl]);
#pragma unroll
    for (int n2 = 0; n2 < 2; ++n2)
#pragma unroll
      for (int kcl = 0; kcl < 4; ++kcl)
        b[n2][kcl] = *(const v4i*)(cbuf + 16384 + (kcl * 4 + nbgl2 + n2) * 1024 + l * 16);
#pragma unroll
    for (int kcl = 0; kcl < 4; ++kcl) {
      ac[0][0] = MFMA_I8(a[0][kcl], b[0][kcl], ac[0][0], 0, 0, 0);
      ac[0][1] = MFMA_I8(a[0][kcl], b[1][kcl], ac[0][1], 0, 0, 0);
      ac[1][0] = MFMA_I8(a[1][kcl], b[0][kcl], ac[1][0], 0, 0, 0);
      ac[1][1] = MFMA_I8(a[1][kcl], b[1][kcl], ac[1][1], 0, 0, 0);
    }
  };

  stageM(0, lds[0]);
  __syncthreads();
  for (int it = 0; it < 17; ++it) {
    stageM(it + 1, lds[(it + 1) & 1]);
    computeM(lds[it & 1], am);
    __syncthreads();
  }
  // stage shortcut (K=128 from px/wsf) into buf0 while computing half-tap 17
  {
    int8_t* buf = lds[0];
#pragma unroll
    for (int i = 0; i < 4; ++i) {
      int ch = w * 4 + i;
      gl_lds16(px + (size_t)sxoff[i] + srcsw, buf + ch * 1024);
      gl_lds16(wsf + ((size_t)(w * 8 + bnh * 4 + i) << 10) + l * 16,
               buf + 16384 + ch * 1024);
    }
  }
  computeM(lds[1], am);                          // it = 17
  __syncthreads();
  v16i as[2][2] = {};
  computeM(lds[0], as);                          // shortcut

  float a2  = stats[1] * (1.f / (CMID * CMID * 9));
  float asx = stats[2] * (1.f / (CMID * CIN));
#pragma unroll
  for (int n2 = 0; n2 < 2; ++n2) {
    int o = waveN + n2 * 32 + l31;
    float ssum = 0.f, ssq = 0.f;
#pragma unroll
    for (int m = 0; m < 2; ++m) {
      int tbase = waveM + m * 32;
      int nb0 = tbase / MPAD, r0 = tbase - nb0 * MPAD;
#pragma unroll
      for (int r = 0; r < 16; ++r) {
        int row = (r & 3) + 8 * (r >> 2) + 4 * lhi;
        int hwr = r0 + row;
        bool valid = hwr < NPIX;
        float v = a2 * (float)am[m][n2][r] + asx * (float)as[m][n2][r];
        if (valid) out[((size_t)nb0 * CMID + o) * NPIX + hwr] = v;
        float vm = valid ? v : 0.f;
        ssum += vm; ssq += vm * vm;
      }
    }
    ssum += __shfl_down(ssum, 32);
    ssq  += __shfl_down(ssq, 32);
    if (l < 32) { atomicAdd(&statw[528 + o], ssum); atomicAdd(&statw[784 + o], ssq); }
  }
}

// BN2 recomputed inline from raw sums (fold of bn2_prep) + apply
__global__ __launch_bounds__(256) void bn2_apply_k(float4* __restrict__ out,
                                                   const float* __restrict__ stats,
                                                   const float* __restrict__ g2,
                                                   const float* __restrict__ b2) {
  int idx = blockIdx.x * 256 + threadIdx.x;       // 3,211,264 float4s = 12544 blocks
  int c = (idx / (NPIX / 4)) & (CMID - 1);
  float S = stats[528 + c], S2 = stats[784 + c];
  float mu = S * (1.f / CNT_CH);
  float var = fmaxf(S2 * (1.f / CNT_CH) - mu * mu, 0.f);
  float rs = rsqrtf(var + EPS_);
  float g = g2[c];
  float sc = g * rs, of = b2[c] - g * rs * mu;
  float4 v = out[idx];
  v.x = v.x * sc + of; v.y = v.y * sc + of; v.z = v.z * sc + of; v.w = v.w * sc + of;
  out[idx] = v;
}

extern "C" void kernel_launch(void* const* d_in, const int* in_sizes, int n_in,
                              void* d_out, int out_size, void* d_ws, size_t ws_size,
                              hipStream_t stream) {
  const float* x   = (const float*)d_in[0];
  const float* w1  = (const float*)d_in[1];
  const float* g1  = (const float*)d_in[2];
  const float* b1  = (const float*)d_in[3];
  const float* w2  = (const float*)d_in[4];
  const float* g2  = (const float*)d_in[5];
  const float* b2  = (const float*)d_in[6];
  const float* wsc = (const float*)d_in[7];
  float* out = (float*)d_out;

  char* ws = (char*)d_ws;
  float*    stats = (float*)ws;
  int8_t*   pxi = (int8_t*)(ws + OFF_PXI);
  int8_t*   pyi = (int8_t*)(ws + OFF_PYI);
  uint32_t* w1f = (uint32_t*)(ws + OFF_W1F);
  uint32_t* w2f = (uint32_t*)(ws + OFF_W2F);
  uint32_t* wsf = (uint32_t*)(ws + OFF_WSF);
  short*    y16 = (short*)d_out;                  // conv1 raw dots, dead after pack_y

  hipMemsetAsync(ws, 0, STATS_BYTES, stream);     // stats only; pads written by packs

  pack_x_k<<<1240, 256, 0, stream>>>(x, pxi);     // 784 interior + 456 pad blocks
  packw_all_k<<<224, 256, 0, stream>>>(w1, w2, wsc, w1f, w2f, wsf, stats);

  conv1_k<<<800, 256, 0, stream>>>(pxi, (const uint8_t*)w1f, y16, stats);
  pack_y_k<<<6736, 256, 0, stream>>>(y16, stats, g1, b1, pyi);  // 6272 + 464 pad
  conv2_k<<<800, 256, 0, stream>>>(pyi, pxi, (const uint8_t*)w2f, (const uint8_t*)wsf,
                                   stats, out, stats);
  bn2_apply_k<<<12544, 256, 0, stream>>>((float4*)out, stats, g2, b2);
}